// Round 11
// baseline (46.824 us; speedup 1.0000x reference)
//
#include <hip/hip_runtime.h>
#include <math.h>

// ExpLogDiceLoss: N x 32 fp32 scores, int32 labels -> scalar loss.
//
// loss_c = pow( log((counts_c + npr_sum_c) / (2 * ni_sum_c)), 0.3 ) for present c
// out = sum_c loss_c / n_present
// where npr_sum_c = sum_rows softmax(score[row])[c]
//       ni_sum_c  = sum_{rows: label==c} softmax(score[row])[c]
//
// SINGLE dispatch + ticket election (R10 post-mortem: the dependent second
// dispatch costs ~10us fixed; R9: cooperative launch rejected; R5: contended
// data atomics cost ~86us). Each block stores exact per-class partials with
// agent-scope coherent stores (issued by wave 0 -> the release fetch_add's
// vmcnt wait orders them), increments a ticket (ACQ_REL, agent). The 512th
// incrementer -- already resident, no spin -- reads all partials with
// agent-scope loads (RMW release sequence => full visibility) and computes
// the scalar epilogue. Deterministic: partials exact, reduce order fixed.
// 4-byte hipMemsetAsync re-zeros the ticket each call (graph-capture-legal).

#define NBLK 512
#define NTHR 1024

__global__ __launch_bounds__(NTHR) void eld_fused(
    const float* __restrict__ score, const int* __restrict__ label,
    float* __restrict__ p_npr, float* __restrict__ p_ni, float* __restrict__ p_cnt,
    unsigned int* __restrict__ ticket,
    float* __restrict__ out,
    int nrows, int ngroups, int nblk)
{
    const int tid   = threadIdx.x;
    const int q     = tid & 7;     // column quarter: classes [4q, 4q+4)
    const int rslot = tid >> 3;    // row slot within a 128-row group
    const int cbase = q << 2;

    float a_npr0 = 0.f, a_npr1 = 0.f, a_npr2 = 0.f, a_npr3 = 0.f;
    float a_ni0  = 0.f, a_ni1  = 0.f, a_ni2  = 0.f, a_ni3  = 0.f;
    float a_c0   = 0.f, a_c1   = 0.f, a_c2   = 0.f, a_c3   = 0.f;

    for (int g = blockIdx.x; g < ngroups; g += gridDim.x) {
        const int row = g * 128 + rslot;
        if (row < nrows) {
            const float4 v = reinterpret_cast<const float4*>(score)[row * 8 + q];
            // row max across 32 classes (8 lanes x 4 elems)
            float m = fmaxf(fmaxf(v.x, v.y), fmaxf(v.z, v.w));
            m = fmaxf(m, __shfl_xor(m, 1));
            m = fmaxf(m, __shfl_xor(m, 2));
            m = fmaxf(m, __shfl_xor(m, 4));
            const float e0 = __expf(v.x - m);
            const float e1 = __expf(v.y - m);
            const float e2 = __expf(v.z - m);
            const float e3 = __expf(v.w - m);
            float s = (e0 + e1) + (e2 + e3);
            s += __shfl_xor(s, 1);
            s += __shfl_xor(s, 2);
            s += __shfl_xor(s, 4);
            const float inv = __builtin_amdgcn_rcpf(s);  // s >= 1, ~1 ulp
            const float p0 = e0 * inv, p1 = e1 * inv, p2 = e2 * inv, p3 = e3 * inv;
            a_npr0 += p0; a_npr1 += p1; a_npr2 += p2; a_npr3 += p3;
            const int lab = label[row];
            // static-indexed predicated accumulate (avoid runtime-indexed arrays)
            if (lab == cbase + 0) { a_ni0 += p0; a_c0 += 1.f; }
            if (lab == cbase + 1) { a_ni1 += p1; a_c1 += 1.f; }
            if (lab == cbase + 2) { a_ni2 += p2; a_c2 += 1.f; }
            if (lab == cbase + 3) { a_ni3 += p3; a_c3 += 1.f; }
        }
    }

    // reduce across the 8 row-slots of each wave (lanes with equal (lane&7))
#pragma unroll
    for (int off = 8; off < 64; off <<= 1) {
        a_npr0 += __shfl_xor(a_npr0, off);
        a_npr1 += __shfl_xor(a_npr1, off);
        a_npr2 += __shfl_xor(a_npr2, off);
        a_npr3 += __shfl_xor(a_npr3, off);
        a_ni0  += __shfl_xor(a_ni0,  off);
        a_ni1  += __shfl_xor(a_ni1,  off);
        a_ni2  += __shfl_xor(a_ni2,  off);
        a_ni3  += __shfl_xor(a_ni3,  off);
        a_c0   += __shfl_xor(a_c0,   off);
        a_c1   += __shfl_xor(a_c1,   off);
        a_c2   += __shfl_xor(a_c2,   off);
        a_c3   += __shfl_xor(a_c3,   off);
    }

    __shared__ float lds[3][16][32];
    const int wave = tid >> 6;
    const int lane = tid & 63;
    if (lane < 8) {
        lds[0][wave][lane * 4 + 0] = a_npr0;
        lds[0][wave][lane * 4 + 1] = a_npr1;
        lds[0][wave][lane * 4 + 2] = a_npr2;
        lds[0][wave][lane * 4 + 3] = a_npr3;
        lds[1][wave][lane * 4 + 0] = a_ni0;
        lds[1][wave][lane * 4 + 1] = a_ni1;
        lds[1][wave][lane * 4 + 2] = a_ni2;
        lds[1][wave][lane * 4 + 3] = a_ni3;
        lds[2][wave][lane * 4 + 0] = a_c0;
        lds[2][wave][lane * 4 + 1] = a_c1;
        lds[2][wave][lane * 4 + 2] = a_c2;
        lds[2][wave][lane * 4 + 3] = a_c3;
    }
    __syncthreads();
    if (tid < 32) {
        float n = 0.f, i2 = 0.f, k = 0.f;
#pragma unroll
        for (int w = 0; w < 16; ++w) {
            n  += lds[0][w][tid];
            i2 += lds[1][w][tid];
            k  += lds[2][w][tid];
        }
        // agent-scope coherent stores (wave 0 only -> ordered by the
        // release fetch_add's vmcnt wait below, also in wave 0)
        __hip_atomic_store(&p_npr[blockIdx.x * 32 + tid], n,
                           __ATOMIC_RELAXED, __HIP_MEMORY_SCOPE_AGENT);
        __hip_atomic_store(&p_ni[blockIdx.x * 32 + tid], i2,
                           __ATOMIC_RELAXED, __HIP_MEMORY_SCOPE_AGENT);
        __hip_atomic_store(&p_cnt[blockIdx.x * 32 + tid], k,
                           __ATOMIC_RELAXED, __HIP_MEMORY_SCOPE_AGENT);
    }
    __syncthreads();

    __shared__ unsigned int elected;
    if (tid == 0) {
        unsigned int old = __hip_atomic_fetch_add(ticket, 1u, __ATOMIC_ACQ_REL,
                                                  __HIP_MEMORY_SCOPE_AGENT);
        elected = (old == (unsigned int)(nblk - 1)) ? 1u : 0u;
    }
    __syncthreads();
    if (!elected) return;

    // ---- elected (last) block: reduce nblk x 32 partials + epilogue ----
    __shared__ float l_npr[32][32], l_ni[32][32], l_cnt[32][32];
    __shared__ float l_loss[32], l_pres[32];
    const int c = tid & 31;
    const int s = tid >> 5;  // 0..31
    float n = 0.f, i2 = 0.f, k = 0.f;
#pragma unroll 16
    for (int b = s; b < nblk; b += 32) {
        n  += __hip_atomic_load(&p_npr[b * 32 + c], __ATOMIC_RELAXED, __HIP_MEMORY_SCOPE_AGENT);
        i2 += __hip_atomic_load(&p_ni[b * 32 + c],  __ATOMIC_RELAXED, __HIP_MEMORY_SCOPE_AGENT);
        k  += __hip_atomic_load(&p_cnt[b * 32 + c], __ATOMIC_RELAXED, __HIP_MEMORY_SCOPE_AGENT);
    }
    l_npr[s][c] = n; l_ni[s][c] = i2; l_cnt[s][c] = k;
    __syncthreads();
    if (tid < 32) {
        float N_ = 0.f, I = 0.f, K = 0.f;
#pragma unroll
        for (int w = 0; w < 32; ++w) { N_ += l_npr[w][tid]; I += l_ni[w][tid]; K += l_cnt[w][tid]; }
        float loss = 0.f, pres = 0.f;
        if (K > 0.f) {
            // neg_log_dice = log((K + npr_sum) / (2*ni_sum)) >= 0
            float nld = logf((K + N_) / (2.f * I));
            nld = fmaxf(nld, 0.f);
            loss = powf(nld, 0.3f);
            pres = 1.f;
        }
        l_loss[tid] = loss;
        l_pres[tid] = pres;
    }
    __syncthreads();
    if (tid == 0) {
        float sum = 0.f, np = 0.f;
#pragma unroll
        for (int c2 = 0; c2 < 32; ++c2) { sum += l_loss[c2]; np += l_pres[c2]; }
        out[0] = sum / np;  // LOSS_WEIGHT = 1
    }
}

extern "C" void kernel_launch(void* const* d_in, const int* in_sizes, int n_in,
                              void* d_out, int out_size, void* d_ws, size_t ws_size,
                              hipStream_t stream) {
    const float* score = (const float*)d_in[0];
    const int*   label = (const int*)d_in[1];
    float* out = (float*)d_out;

    const int nrows = in_sizes[0] / 32;
    const int ngroups = (nrows + 127) / 128;

    int nblk = NBLK;
    if (nblk > ngroups) nblk = ngroups;

    float* p_npr = (float*)d_ws;                         // [nblk*32]
    float* p_ni  = p_npr + (size_t)NBLK * 32;
    float* p_cnt = p_ni  + (size_t)NBLK * 32;
    unsigned int* ticket = (unsigned int*)(p_cnt + (size_t)NBLK * 32);

    hipMemsetAsync(ticket, 0, sizeof(unsigned int), stream);

    eld_fused<<<nblk, NTHR, 0, stream>>>(score, label, p_npr, p_ni, p_cnt,
                                         ticket, out, nrows, ngroups, nblk);
}

// Round 12
// 35.922 us; speedup vs baseline: 1.3035x; 1.3035x over previous
//
#include <hip/hip_runtime.h>
#include <math.h>

// ExpLogDiceLoss: N x 32 fp32 scores, int32 labels -> scalar loss.
//
// loss_c = pow( log((counts_c + npr_sum_c) / (2 * ni_sum_c)), 0.3 ) for present c
// out = sum_c loss_c / n_present
// where npr_sum_c = sum_rows softmax(score[row])[c]
//       ni_sum_c  = sum_{rows: label==c} softmax(score[row])[c]
//
// Three dispatches (R5/R9/R11: all single-dispatch fusions lose; R3 decomp:
// pass1(2048x256)+gaps ~ 21us; R4/R8: per-thread strided reduction over 64+
// partials is a 0.3us/iter latency chain). Pass1: 2048x256, partials stored
// CLASS-MAJOR p[class][block] so the block-reduction is contiguous.
// Pass2: 32 blocks (one per class) x 256 threads, 8 coalesced loads/thread,
// fully parallel across blocks -> no latency chain; per-class loss to tiny[].
// Pass3: one wave sums the 32 losses -> scalar. All fixed-order, deterministic.

#define NBLK1 2048
#define NTHR1 256

__global__ __launch_bounds__(NTHR1) void eld_pass1(
    const float* __restrict__ score, const int* __restrict__ label,
    float* __restrict__ part,   // [96][nblk]: npr c*nblk | ni (32+c)*nblk | cnt (64+c)*nblk
    int nrows, int ngroups, int nblk)
{
    const int tid   = threadIdx.x;
    const int q     = tid & 7;     // column quarter: classes [4q, 4q+4)
    const int rslot = tid >> 3;    // row slot within a 32-row group
    const int cbase = q << 2;

    float a_npr0 = 0.f, a_npr1 = 0.f, a_npr2 = 0.f, a_npr3 = 0.f;
    float a_ni0  = 0.f, a_ni1  = 0.f, a_ni2  = 0.f, a_ni3  = 0.f;
    float a_c0   = 0.f, a_c1   = 0.f, a_c2   = 0.f, a_c3   = 0.f;

    for (int g = blockIdx.x; g < ngroups; g += gridDim.x) {
        const int row = g * 32 + rslot;
        if (row < nrows) {
            const float4 v = reinterpret_cast<const float4*>(score)[row * 8 + q];
            // row max across 32 classes (8 lanes x 4 elems)
            float m = fmaxf(fmaxf(v.x, v.y), fmaxf(v.z, v.w));
            m = fmaxf(m, __shfl_xor(m, 1));
            m = fmaxf(m, __shfl_xor(m, 2));
            m = fmaxf(m, __shfl_xor(m, 4));
            const float e0 = __expf(v.x - m);
            const float e1 = __expf(v.y - m);
            const float e2 = __expf(v.z - m);
            const float e3 = __expf(v.w - m);
            float s = (e0 + e1) + (e2 + e3);
            s += __shfl_xor(s, 1);
            s += __shfl_xor(s, 2);
            s += __shfl_xor(s, 4);
            const float inv = __builtin_amdgcn_rcpf(s);  // s >= 1, ~1 ulp
            const float p0 = e0 * inv, p1 = e1 * inv, p2 = e2 * inv, p3 = e3 * inv;
            a_npr0 += p0; a_npr1 += p1; a_npr2 += p2; a_npr3 += p3;
            const int lab = label[row];
            // static-indexed predicated accumulate (avoid runtime-indexed arrays)
            if (lab == cbase + 0) { a_ni0 += p0; a_c0 += 1.f; }
            if (lab == cbase + 1) { a_ni1 += p1; a_c1 += 1.f; }
            if (lab == cbase + 2) { a_ni2 += p2; a_c2 += 1.f; }
            if (lab == cbase + 3) { a_ni3 += p3; a_c3 += 1.f; }
        }
    }

    // reduce across the 8 row-slots of each wave (lanes with equal (lane&7))
#pragma unroll
    for (int off = 8; off < 64; off <<= 1) {
        a_npr0 += __shfl_xor(a_npr0, off);
        a_npr1 += __shfl_xor(a_npr1, off);
        a_npr2 += __shfl_xor(a_npr2, off);
        a_npr3 += __shfl_xor(a_npr3, off);
        a_ni0  += __shfl_xor(a_ni0,  off);
        a_ni1  += __shfl_xor(a_ni1,  off);
        a_ni2  += __shfl_xor(a_ni2,  off);
        a_ni3  += __shfl_xor(a_ni3,  off);
        a_c0   += __shfl_xor(a_c0,   off);
        a_c1   += __shfl_xor(a_c1,   off);
        a_c2   += __shfl_xor(a_c2,   off);
        a_c3   += __shfl_xor(a_c3,   off);
    }

    __shared__ float lds[3][4][32];
    const int wave = tid >> 6;
    const int lane = tid & 63;
    if (lane < 8) {
        lds[0][wave][lane * 4 + 0] = a_npr0;
        lds[0][wave][lane * 4 + 1] = a_npr1;
        lds[0][wave][lane * 4 + 2] = a_npr2;
        lds[0][wave][lane * 4 + 3] = a_npr3;
        lds[1][wave][lane * 4 + 0] = a_ni0;
        lds[1][wave][lane * 4 + 1] = a_ni1;
        lds[1][wave][lane * 4 + 2] = a_ni2;
        lds[1][wave][lane * 4 + 3] = a_ni3;
        lds[2][wave][lane * 4 + 0] = a_c0;
        lds[2][wave][lane * 4 + 1] = a_c1;
        lds[2][wave][lane * 4 + 2] = a_c2;
        lds[2][wave][lane * 4 + 3] = a_c3;
    }
    __syncthreads();
    if (tid < 32) {
        float n = 0.f, i2 = 0.f, k = 0.f;
#pragma unroll
        for (int w = 0; w < 4; ++w) {
            n  += lds[0][w][tid];
            i2 += lds[1][w][tid];
            k  += lds[2][w][tid];
        }
        // class-major scatter: contiguous per-class rows for pass2
        part[(size_t)tid * nblk + blockIdx.x]        = n;
        part[(size_t)(32 + tid) * nblk + blockIdx.x] = i2;
        part[(size_t)(64 + tid) * nblk + blockIdx.x] = k;
    }
}

// 32 blocks (one per class) x 256 threads: coalesced contiguous reduction,
// all blocks parallel -> no serialized latency chain.
__global__ __launch_bounds__(256) void eld_pass2(
    const float* __restrict__ part, float* __restrict__ tiny, int nblk)
{
    const int c = blockIdx.x;
    const int tid = threadIdx.x;
    const float* npr = part + (size_t)c * nblk;
    const float* ni  = part + (size_t)(32 + c) * nblk;
    const float* cnt = part + (size_t)(64 + c) * nblk;

    float n = 0.f, i2 = 0.f, k = 0.f;
    for (int b = tid; b < nblk; b += 256) {
        n += npr[b]; i2 += ni[b]; k += cnt[b];
    }
#pragma unroll
    for (int off = 1; off < 64; off <<= 1) {
        n  += __shfl_xor(n, off);
        i2 += __shfl_xor(i2, off);
        k  += __shfl_xor(k, off);
    }
    __shared__ float ln[4], li[4], lk[4];
    const int wave = tid >> 6;
    if ((tid & 63) == 0) { ln[wave] = n; li[wave] = i2; lk[wave] = k; }
    __syncthreads();
    if (tid == 0) {
        float N_ = ln[0] + ln[1] + ln[2] + ln[3];
        float I  = li[0] + li[1] + li[2] + li[3];
        float K  = lk[0] + lk[1] + lk[2] + lk[3];
        float loss = 0.f, pres = 0.f;
        if (K > 0.f) {
            float nld = logf((K + N_) / (2.f * I));   // >= 0 by construction
            nld = fmaxf(nld, 0.f);
            loss = powf(nld, 0.3f);
            pres = 1.f;
        }
        tiny[c]      = loss;
        tiny[32 + c] = pres;
    }
}

// One wave: sum 32 losses / presence -> scalar.
__global__ __launch_bounds__(64) void eld_pass3(
    const float* __restrict__ tiny, float* __restrict__ out)
{
    const int lane = threadIdx.x;
    float l = (lane < 32) ? tiny[lane]      : 0.f;
    float p = (lane < 32) ? tiny[32 + lane] : 0.f;
#pragma unroll
    for (int off = 1; off < 64; off <<= 1) {
        l += __shfl_xor(l, off);
        p += __shfl_xor(p, off);
    }
    if (lane == 0) out[0] = l / p;   // LOSS_WEIGHT = 1
}

extern "C" void kernel_launch(void* const* d_in, const int* in_sizes, int n_in,
                              void* d_out, int out_size, void* d_ws, size_t ws_size,
                              hipStream_t stream) {
    const float* score = (const float*)d_in[0];
    const int*   label = (const int*)d_in[1];
    float* out = (float*)d_out;

    const int nrows = in_sizes[0] / 32;
    const int ngroups = (nrows + 31) / 32;

    int nblk = NBLK1;
    if (nblk > ngroups) nblk = ngroups;

    float* part = (float*)d_ws;                      // [96 * nblk]
    float* tiny = part + (size_t)96 * nblk;          // [64]

    eld_pass1<<<nblk, NTHR1, 0, stream>>>(score, label, part, nrows, ngroups, nblk);
    eld_pass2<<<32, 256, 0, stream>>>(part, tiny, nblk);
    eld_pass3<<<1, 64, 0, stream>>>(tiny, out);
}